// Round 12
// baseline (170.586 us; speedup 1.0000x reference)
//
#include <hip/hip_runtime.h>
#include <hip/hip_bf16.h>
#include <stdint.h>
#include <stddef.h>

#define DIM   2048
#define NEXP  64
#define NTOK  32768
#define KF    64                       // 2048/32 k-fragments (global)
#define OFF_IDX  (NTOK*NEXP)           // 2097152
#define OFF_TSC  (OFF_IDX + NTOK*2)    // 2162688
#define TAU   5e-4f

typedef __attribute__((ext_vector_type(8))) short  short8;
typedef __attribute__((ext_vector_type(4))) float  f32x4;

__device__ __forceinline__ unsigned short bf16_rne(float f) {
    unsigned u = __builtin_bit_cast(unsigned, f);
    u += 0x7fffu + ((u >> 16) & 1u);
    return (unsigned short)(u >> 16);
}
__device__ __forceinline__ float bf16_up(unsigned short s) {
    unsigned u = ((unsigned)s) << 16;
    return __builtin_bit_cast(float, u);
}

// ---------------------------------------------------------------------------
// Pre-kernel: split W into 2 bf16 terms (hi/mid) in MFMA B-fragment order.
// Also zeroes the ambiguous-token counter.
// ---------------------------------------------------------------------------
__global__ __launch_bounds__(256) void wsplit(const float* __restrict__ W,
                                              short* __restrict__ warr,
                                              int* __restrict__ cnt) {
    int idx  = blockIdx.x * 256 + threadIdx.x;   // 0..262143
    if (idx == 0) *cnt = 0;
    int j    = idx & 7;
    int lane = (idx >> 3) & 63;
    int nf   = (idx >> 9) & 3;
    int kf   = (idx >> 11) & 63;
    int term = idx >> 17;                        // 0..1
    int e = nf * 16 + (lane & 15);
    int d = kf * 32 + (lane >> 4) * 8 + j;
    float w = W[e * DIM + d];
    unsigned short h  = bf16_rne(w);
    float r1 = w - bf16_up(h);
    unsigned short md = bf16_rne(r1);
    warr[idx] = (short)((term == 0) ? h : md);
}

__device__ __forceinline__ bool gtie(float a, int ia, float b, int ib) {
    return (a > b) || (a == b && ia < ib);
}

// ---------------------------------------------------------------------------
// Kernel A (R12): templated replica probe. NCH=8/FINAL=true is byte-identical
// to the R11-passing kernel. NCH=4/FINAL=false is a half-scale replica:
// same loads/split/MFMA for kf 0..31, NO stores (acc kept alive via asm) --
// measures router_mfma's true marginal cost: full ~= 2*(dur_R12 - dur_R11).
// ---------------------------------------------------------------------------
template <int NCH, bool FINAL>
__global__ __launch_bounds__(256, 2) void router_mfma(
        const float* __restrict__ X, const short* __restrict__ Wsp,
        const float* __restrict__ bias, float* __restrict__ out,
        int* __restrict__ cnt, int* __restrict__ list) {
    __shared__ char xtile[4][16384] __attribute__((aligned(16)));
    const int lane = threadIdx.x & 63;
    const int wid  = threadIdx.x >> 6;         // 0..3
    const int tok0 = blockIdx.x * 64 + wid * 16;
    const int l15  = lane & 15;
    const int l4   = lane >> 4;
    char* xt = xtile[wid];

    const float* xg = X + (size_t)tok0 * DIM + lane * 4;
    const int rbase = l15 * 1024;
    const int rsw   = (l15 & 7) << 4;
    const int cbyte = l4 * 32;

    const short8* wp = (const short8*)Wsp + lane;  // + ((t*KF+kf)*4+n)*64

    f32x4 acc[4];
#pragma unroll
    for (int n = 0; n < 4; n++) acc[n] = (f32x4)0.0f;

    // ---- prologue: stage chunk 0 (16 rows x 1KB contiguous each) ----------
    {
        f32x4 st[16];
#pragma unroll
        for (int r = 0; r < 16; r++) st[r] = *(const f32x4*)(xg + (size_t)r * DIM);
#pragma unroll
        for (int r = 0; r < 16; r++)
            *(f32x4*)(xt + r * 1024 + ((lane * 16) ^ ((r & 7) << 4))) = st[r];
    }
    short8 b_pf[2][2][4];
#pragma unroll
    for (int t = 0; t < 2; t++)
#pragma unroll
        for (int n = 0; n < 4; n++)
            b_pf[0][t][n] = wp[((t * KF + 0) * 4 + n) * 64];

#pragma unroll 1
    for (int ch = 0; ch < NCH; ++ch) {
        f32x4 st[16];
        if (ch < NCH - 1) {
#pragma unroll
            for (int r = 0; r < 16; r++)
                st[r] = *(const f32x4*)(xg + (size_t)r * DIM + (ch + 1) * 256);
        }

#pragma unroll
        for (int q = 0; q < 8; ++q) {
            const int kf  = ch * 8 + q;
            const int kfn = (kf + 1 < KF) ? kf + 1 : KF - 1;

#pragma unroll
            for (int t = 0; t < 2; t++)
#pragma unroll
                for (int n = 0; n < 4; n++)
                    b_pf[(q + 1) & 1][t][n] = wp[((t * KF + kfn) * 4 + n) * 64];

            const int b0 = q * 128 + cbyte;
            f32x4 a0 = *(const f32x4*)(xt + rbase + ((b0)      ^ rsw));
            f32x4 a1 = *(const f32x4*)(xt + rbase + ((b0 + 16) ^ rsw));

            short8 ah, am;
#pragma unroll
            for (int j = 0; j < 8; j++) {
                float v = (j < 4) ? a0[j & 3] : a1[j & 3];
                unsigned short h  = bf16_rne(v);
                float r1 = v - bf16_up(h);
                unsigned short md = bf16_rne(r1);
                ah[j] = (short)h;
                am[j] = (short)md;
            }

#pragma unroll
            for (int n = 0; n < 4; n++) {
                f32x4 c = acc[n];
                c = __builtin_amdgcn_mfma_f32_16x16x32_bf16(ah, b_pf[q & 1][0][n], c, 0, 0, 0);
                c = __builtin_amdgcn_mfma_f32_16x16x32_bf16(ah, b_pf[q & 1][1][n], c, 0, 0, 0);
                c = __builtin_amdgcn_mfma_f32_16x16x32_bf16(am, b_pf[q & 1][0][n], c, 0, 0, 0);
                c = __builtin_amdgcn_mfma_f32_16x16x32_bf16(am, b_pf[q & 1][1][n], c, 0, 0, 0);
                acc[n] = c;
            }
        }

        if (ch < NCH - 1) {
#pragma unroll
            for (int r = 0; r < 16; r++)
                *(f32x4*)(xt + r * 1024 + ((lane * 16) ^ ((r & 7) << 4))) = st[r];
        }
    }

    if constexpr (!FINAL) {
        // probe pass: no stores; keep the computation live (rule #17)
#pragma unroll
        for (int n = 0; n < 4; n++) {
            asm volatile("" :: "v"(acc[n][0]), "v"(acc[n][1]),
                              "v"(acc[n][2]), "v"(acc[n][3]));
        }
        return;
    }

    // ------------- epilogue: bias + softmax + top-3 + flag (R8-verified) ---
    float bv[4];
#pragma unroll
    for (int n = 0; n < 4; n++) bv[n] = bias[n * 16 + l15];

#pragma unroll
    for (int r = 0; r < 4; r++) {
        const int t = tok0 + l4 * 4 + r;       // C row = (lane>>4)*4+reg
        float v[4];
#pragma unroll
        for (int n = 0; n < 4; n++) v[n] = acc[n][r] + bv[n];

        float mx = fmaxf(fmaxf(v[0], v[1]), fmaxf(v[2], v[3]));
#pragma unroll
        for (int s = 1; s < 16; s <<= 1) mx = fmaxf(mx, __shfl_xor(mx, s, 64));

        float p[4], den = 0.0f;
#pragma unroll
        for (int n = 0; n < 4; n++) { p[n] = __expf(v[n] - mx); den += p[n]; }
#pragma unroll
        for (int s = 1; s < 16; s <<= 1) den += __shfl_xor(den, s, 64);
        const float inv = 1.0f / den;
#pragma unroll
        for (int n = 0; n < 4; n++)
            out[(size_t)t * 64 + n * 16 + l15] = p[n] * inv;

        float v1 = -3.4e38f, v2 = -3.4e38f, v3 = -3.4e38f;
        int   i1 = 9999,     i2 = 9999,     i3 = 9999;
#pragma unroll
        for (int n = 0; n < 4; n++) {
            float vv = v[n]; int ii = n * 16 + l15;
            if (gtie(vv, ii, v1, i1))      { v3=v2;i3=i2; v2=v1;i2=i1; v1=vv;i1=ii; }
            else if (gtie(vv, ii, v2, i2)) { v3=v2;i3=i2; v2=vv;i2=ii; }
            else if (gtie(vv, ii, v3, i3)) { v3=vv;i3=ii; }
        }
#pragma unroll
        for (int s = 1; s < 16; s <<= 1) {
            float ov1=__shfl_xor(v1,s,64), ov2=__shfl_xor(v2,s,64), ov3=__shfl_xor(v3,s,64);
            int   oi1=__shfl_xor(i1,s,64), oi2=__shfl_xor(i2,s,64), oi3=__shfl_xor(i3,s,64);
            bool a1 = gtie(v1,i1,ov1,oi1);
            float w1 = a1?v1:ov1;  int k1 = a1?i1:oi1;
            float x1 = a1?v2:ov2;  int xi1= a1?i2:oi2;
            float x2 = a1?v3:ov3;  int xi2= a1?i3:oi3;
            float y1 = a1?ov1:v1;  int yi1= a1?oi1:i1;
            float y2 = a1?ov2:v2;  int yi2= a1?oi2:i2;
            bool a2 = gtie(x1,xi1,y1,yi1);
            float w2 = a2?x1:y1;   int k2 = a2?xi1:yi1;
            float w3; int k3;
            if (a2) { bool a3 = gtie(x2,xi2,y1,yi1); w3 = a3?x2:y1; k3 = a3?xi2:yi1; }
            else    { bool a3 = gtie(x1,xi1,y2,yi2); w3 = a3?x1:y2; k3 = a3?xi1:yi2; }
            v1=w1;i1=k1; v2=w2;i2=k2; v3=w3;i3=k3;
        }
        if (l15 == 0) {
            out[OFF_IDX + (size_t)t * 2 + 0] = (float)i1;
            out[OFF_IDX + (size_t)t * 2 + 1] = (float)i2;
            out[OFF_TSC + (size_t)t * 2 + 0] = __expf(v1 - mx) * inv;
            out[OFF_TSC + (size_t)t * 2 + 1] = __expf(v2 - mx) * inv;
            if ((v1 - v2 < TAU) || (v2 - v3 < TAU)) {
                int slot = atomicAdd(cnt, 1);
                list[slot] = t;
            }
        }
    }
}

// ---------------------------------------------------------------------------
// Kernel B: exact np-chain recompute for flagged tokens (R3-R11 verified).
// ---------------------------------------------------------------------------
__global__ __launch_bounds__(256, 2) void router_exact(
        const float* __restrict__ X, const float* __restrict__ W,
        const float* __restrict__ Bb, float* __restrict__ out,
        const int* __restrict__ cnt, const int* __restrict__ list) {
    __shared__ float xrow[2048];
    __shared__ char  wbuf[2][64 * 272] __attribute__((aligned(16)));
    const int tid = threadIdx.x;
    const int n   = *cnt;

    for (int ii = blockIdx.x; ii < n; ii += gridDim.x) {
        const int t = list[ii];
#pragma unroll
        for (int q = 0; q < 2; ++q) {
            int s = tid + q * 256;
            *(f32x4*)&xrow[s * 4] = *(const f32x4*)(X + (size_t)t * DIM + s * 4);
        }
#pragma unroll
        for (int q = 0; q < 4; ++q) {
            int s = tid + q * 256;
            int e = s >> 4, dq = s & 15;
            f32x4 wv = *(const f32x4*)(W + (size_t)e * DIM + dq * 4);
            *(f32x4*)(wbuf[0] + e * 272 + ((16 * dq) ^ ((e & 7) << 4))) = wv;
        }
        __syncthreads();

        float acc = 0.0f;
#pragma unroll 1
        for (int c = 0; c < 32; ++c) {
            if (c + 1 < 32) {
#pragma unroll
                for (int q = 0; q < 4; ++q) {
                    int s = tid + q * 256;
                    int e = s >> 4, dq = s & 15;
                    f32x4 wv = *(const f32x4*)(W + (size_t)e * DIM + (c + 1) * 64 + dq * 4);
                    *(f32x4*)(wbuf[(c + 1) & 1] + e * 272 + ((16 * dq) ^ ((e & 7) << 4))) = wv;
                }
            }
            if (tid < 64) {
                const char* wb = wbuf[c & 1] + tid * 272;
                const int sw = (tid & 7) << 4;
#pragma unroll
                for (int dq = 0; dq < 16; ++dq) {
                    f32x4 xq = *(const f32x4*)&xrow[c * 64 + dq * 4];
                    f32x4 wv = *(const f32x4*)(wb + ((16 * dq) ^ sw));
#pragma unroll
                    for (int j = 0; j < 4; ++j)
                        acc = fmaf(xq[j], wv[j], acc);   // strict ascending d
                }
            }
            __syncthreads();
        }

        if (tid < 64) {
            const int lane = tid;
            const float lg = acc + Bb[lane];
            float m = lg;
#pragma unroll
            for (int s = 1; s < 64; s <<= 1) m = fmaxf(m, __shfl_xor(m, s, 64));
            const float p = __expf(lg - m);
            float den = p;
#pragma unroll
            for (int s = 1; s < 64; s <<= 1) den += __shfl_xor(den, s, 64);
            const float inv = 1.0f / den;
            out[(size_t)t * 64 + lane] = p * inv;

            float v1 = lg, v2 = -3.4e38f;
            int   i1 = lane, i2 = 127;
#pragma unroll
            for (int s = 1; s < 64; s <<= 1) {
                float ov1 = __shfl_xor(v1, s, 64), ov2 = __shfl_xor(v2, s, 64);
                int   oi1 = __shfl_xor(i1, s, 64), oi2 = __shfl_xor(i2, s, 64);
                bool  aw  = gtie(v1, i1, ov1, oi1);
                float nv1 = aw ? v1 : ov1;  int ni1 = aw ? i1 : oi1;
                float cv  = aw ? ov1 : v1;  int ci  = aw ? oi1 : i1;
                float sv  = aw ? v2 : ov2;  int si  = aw ? i2 : oi2;
                bool  c2  = gtie(cv, ci, sv, si);
                v1 = nv1; i1 = ni1;
                v2 = c2 ? cv : sv; i2 = c2 ? ci : si;
            }
            if (lane == 0) {
                out[OFF_IDX + (size_t)t * 2 + 0] = (float)i1;
                out[OFF_IDX + (size_t)t * 2 + 1] = (float)i2;
                out[OFF_TSC + (size_t)t * 2 + 0] = __expf(v1 - m) * inv;
                out[OFF_TSC + (size_t)t * 2 + 1] = __expf(v2 - m) * inv;
            }
        }
        __syncthreads();
    }
}

extern "C" void kernel_launch(void* const* d_in, const int* in_sizes, int n_in,
                              void* d_out, int out_size, void* d_ws, size_t ws_size,
                              hipStream_t stream) {
    const float* X = (const float*)d_in[0];   // [4,8192,2048] f32
    const float* W = (const float*)d_in[1];   // [64,2048] f32
    const float* b = (const float*)d_in[2];   // [64] f32
    float* out  = (float*)d_out;
    short* Wsp  = (short*)d_ws;                       // 512 KB
    int*   cnt  = (int*)((char*)d_ws + 524288);       // 4 B
    int*   list = (int*)((char*)d_ws + 524292);       // up to 128 KB

    wsplit<<<1024, 256, 0, stream>>>(W, Wsp, cnt);
    // half-scale replica probe (no stores): measures marginal kernel cost
    router_mfma<4, false><<<NTOK / 64, 256, 0, stream>>>(X, Wsp, b, out, cnt, list);
    // real pass — byte-identical behavior to the R11-passing kernel
    router_mfma<8, true><<<NTOK / 64, 256, 0, stream>>>(X, Wsp, b, out, cnt, list);
    router_exact<<<512, 256, 0, stream>>>(X, W, b, out, cnt, list);
}

// Round 14
// 167.394 us; speedup vs baseline: 1.0191x; 1.0191x over previous
//
#include <hip/hip_runtime.h>
#include <hip/hip_bf16.h>
#include <stdint.h>
#include <stddef.h>

#define DIM   2048
#define NEXP  64
#define NTOK  32768
#define KF    64                       // 2048/32 k-fragments (global)
#define OFF_IDX  (NTOK*NEXP)           // 2097152
#define OFF_TSC  (OFF_IDX + NTOK*2)    // 2162688
#define TAU   5e-4f

typedef __attribute__((ext_vector_type(8))) short  short8;
typedef __attribute__((ext_vector_type(4))) float  f32x4;

__device__ __forceinline__ unsigned short bf16_rne(float f) {
    unsigned u = __builtin_bit_cast(unsigned, f);
    u += 0x7fffu + ((u >> 16) & 1u);
    return (unsigned short)(u >> 16);
}
__device__ __forceinline__ float bf16_up(unsigned short s) {
    unsigned u = ((unsigned)s) << 16;
    return __builtin_bit_cast(float, u);
}

// ---------------------------------------------------------------------------
// Pre-kernel: split W into 2 bf16 terms (hi/mid) in MFMA B-fragment order.
// Also zeroes the ambiguous-token counter.
// ---------------------------------------------------------------------------
__global__ __launch_bounds__(256) void wsplit(const float* __restrict__ W,
                                              short* __restrict__ warr,
                                              int* __restrict__ cnt) {
    int idx  = blockIdx.x * 256 + threadIdx.x;   // 0..262143
    if (idx == 0) *cnt = 0;
    int j    = idx & 7;
    int lane = (idx >> 3) & 63;
    int nf   = (idx >> 9) & 3;
    int kf   = (idx >> 11) & 63;
    int term = idx >> 17;                        // 0..1
    int e = nf * 16 + (lane & 15);
    int d = kf * 32 + (lane >> 4) * 8 + j;
    float w = W[e * DIM + d];
    unsigned short h  = bf16_rne(w);
    float r1 = w - bf16_up(h);
    unsigned short md = bf16_rne(r1);
    warr[idx] = (short)((term == 0) ? h : md);
}

__device__ __forceinline__ bool gtie(float a, int ia, float b, int ib) {
    return (a > b) || (a == b && ia < ib);
}

// ---------------------------------------------------------------------------
// Kernel A (R14): R13 with the staging bug fixed. Staging now follows R11's
// VERIFIED pattern: LINEAR global read -> swizzled ds_write -> swizzled
// ds_read (the XOR involution appears once on each LDS side only; R13
// wrongly also swizzled the global source = double-swizzle = identity).
// 1-wave (64-thr) blocks, 2048 blocks -> 16 waves/CU on all 256 CUs
// (4/SIMD). Private 8KB LDS, chunk = 128 dims, T14 load-early/write-late,
// direct per-kf B loads (L1-hot). No barriers anywhere.
// Numerics + epilogue + TAU flag byte-identical to R8-R12 (all passed).
// ---------------------------------------------------------------------------
__global__ __launch_bounds__(64, 4) void router_mfma(
        const float* __restrict__ X, const short* __restrict__ Wsp,
        const float* __restrict__ bias, float* __restrict__ out,
        int* __restrict__ cnt, int* __restrict__ list) {
    __shared__ char xt[8192] __attribute__((aligned(16)));   // [16 rows][512B]
    const int lane = threadIdx.x;              // 0..63 (1 wave/block)
    const int tok0 = blockIdx.x * 16;
    const int l15  = lane & 15;
    const int l4   = lane >> 4;

    // staging: instr i (0..7): row r = i*2 + (lane>>5), 32 lanes cover 512B.
    // global: LINEAR col (lane&31)*16 bytes; LDS: byte ^ ((r&7)<<4).
    const int r_lo  = lane >> 5;               // 0 or 1
    const int c_lin = (lane & 31) * 16;        // linear byte col in chunk

    const short8* wp = (const short8*)Wsp + lane;  // + ((t*KF+kf)*4+n)*64

    // read map: row l15, swizzle ((l15&7)<<4)
    const int rbase = l15 * 512;
    const int rsw   = (l15 & 7) << 4;
    const int cbyte = l4 * 32;

    f32x4 acc[4];
#pragma unroll
    for (int n = 0; n < 4; n++) acc[n] = (f32x4)0.0f;

    // ---- prologue: stage chunk 0 ------------------------------------------
    {
        f32x4 st[8];
#pragma unroll
        for (int i = 0; i < 8; i++) {
            const int r = i * 2 + r_lo;
            st[i] = *(const f32x4*)(X + (size_t)(tok0 + r) * DIM + c_lin / 4);
        }
#pragma unroll
        for (int i = 0; i < 8; i++) {
            const int r = i * 2 + r_lo;
            *(f32x4*)(xt + r * 512 + (c_lin ^ ((r & 7) << 4))) = st[i];
        }
    }

#pragma unroll 1
    for (int ch = 0; ch < 16; ++ch) {
        // T14: issue next chunk's loads first; pin them above compute
        f32x4 st[8];
        if (ch < 15) {
#pragma unroll
            for (int i = 0; i < 8; i++) {
                const int r = i * 2 + r_lo;
                st[i] = *(const f32x4*)(X + (size_t)(tok0 + r) * DIM
                                        + (ch + 1) * 128 + c_lin / 4);
            }
            __builtin_amdgcn_sched_barrier(0);
        }

#pragma unroll
        for (int q = 0; q < 4; ++q) {
            const int kf = ch * 4 + q;

            // B direct load for this kf (L1-hot; TLP hides latency)
            short8 b[2][4];
#pragma unroll
            for (int t = 0; t < 2; t++)
#pragma unroll
                for (int n = 0; n < 4; n++)
                    b[t][n] = wp[((t * KF + kf) * 4 + n) * 64];

            // A fragment from LDS (swizzled)
            const int b0 = q * 128 + cbyte;
            f32x4 a0 = *(const f32x4*)(xt + rbase + ((b0)      ^ rsw));
            f32x4 a1 = *(const f32x4*)(xt + rbase + ((b0 + 16) ^ rsw));

            // 2-way bf16 split of A (identical math to R8)
            short8 ah, am;
#pragma unroll
            for (int j = 0; j < 8; j++) {
                float v = (j < 4) ? a0[j & 3] : a1[j & 3];
                unsigned short h  = bf16_rne(v);
                float r1 = v - bf16_up(h);
                unsigned short md = bf16_rne(r1);
                ah[j] = (short)h;
                am[j] = (short)md;
            }

#pragma unroll
            for (int n = 0; n < 4; n++) {
                f32x4 c = acc[n];
                c = __builtin_amdgcn_mfma_f32_16x16x32_bf16(ah, b[0][n], c, 0, 0, 0);
                c = __builtin_amdgcn_mfma_f32_16x16x32_bf16(ah, b[1][n], c, 0, 0, 0);
                c = __builtin_amdgcn_mfma_f32_16x16x32_bf16(am, b[0][n], c, 0, 0, 0);
                c = __builtin_amdgcn_mfma_f32_16x16x32_bf16(am, b[1][n], c, 0, 0, 0);
                acc[n] = c;
            }
        }

        if (ch < 15) {
#pragma unroll
            for (int i = 0; i < 8; i++) {
                const int r = i * 2 + r_lo;
                *(f32x4*)(xt + r * 512 + (c_lin ^ ((r & 7) << 4))) = st[i];
            }
        }
    }

    // ------------- epilogue: bias + softmax + top-3 + flag (R8-verified) ---
    float bv[4];
#pragma unroll
    for (int n = 0; n < 4; n++) bv[n] = bias[n * 16 + l15];

#pragma unroll
    for (int r = 0; r < 4; r++) {
        const int t = tok0 + l4 * 4 + r;       // C row = (lane>>4)*4+reg
        float v[4];
#pragma unroll
        for (int n = 0; n < 4; n++) v[n] = acc[n][r] + bv[n];

        float mx = fmaxf(fmaxf(v[0], v[1]), fmaxf(v[2], v[3]));
#pragma unroll
        for (int s = 1; s < 16; s <<= 1) mx = fmaxf(mx, __shfl_xor(mx, s, 64));

        float p[4], den = 0.0f;
#pragma unroll
        for (int n = 0; n < 4; n++) { p[n] = __expf(v[n] - mx); den += p[n]; }
#pragma unroll
        for (int s = 1; s < 16; s <<= 1) den += __shfl_xor(den, s, 64);
        const float inv = 1.0f / den;
#pragma unroll
        for (int n = 0; n < 4; n++)
            out[(size_t)t * 64 + n * 16 + l15] = p[n] * inv;

        float v1 = -3.4e38f, v2 = -3.4e38f, v3 = -3.4e38f;
        int   i1 = 9999,     i2 = 9999,     i3 = 9999;
#pragma unroll
        for (int n = 0; n < 4; n++) {
            float vv = v[n]; int ii = n * 16 + l15;
            if (gtie(vv, ii, v1, i1))      { v3=v2;i3=i2; v2=v1;i2=i1; v1=vv;i1=ii; }
            else if (gtie(vv, ii, v2, i2)) { v3=v2;i3=i2; v2=vv;i2=ii; }
            else if (gtie(vv, ii, v3, i3)) { v3=vv;i3=ii; }
        }
#pragma unroll
        for (int s = 1; s < 16; s <<= 1) {
            float ov1=__shfl_xor(v1,s,64), ov2=__shfl_xor(v2,s,64), ov3=__shfl_xor(v3,s,64);
            int   oi1=__shfl_xor(i1,s,64), oi2=__shfl_xor(i2,s,64), oi3=__shfl_xor(i3,s,64);
            bool a1 = gtie(v1,i1,ov1,oi1);
            float w1 = a1?v1:ov1;  int k1 = a1?i1:oi1;
            float x1 = a1?v2:ov2;  int xi1= a1?i2:oi2;
            float x2 = a1?v3:ov3;  int xi2= a1?i3:oi3;
            float y1 = a1?ov1:v1;  int yi1= a1?oi1:i1;
            float y2 = a1?ov2:v2;  int yi2= a1?oi2:i2;
            bool a2 = gtie(x1,xi1,y1,yi1);
            float w2 = a2?x1:y1;   int k2 = a2?xi1:yi1;
            float w3; int k3;
            if (a2) { bool a3 = gtie(x2,xi2,y1,yi1); w3 = a3?x2:y1; k3 = a3?xi2:yi1; }
            else    { bool a3 = gtie(x1,xi1,y2,yi2); w3 = a3?x1:y2; k3 = a3?xi1:yi2; }
            v1=w1;i1=k1; v2=w2;i2=k2; v3=w3;i3=k3;
        }
        if (l15 == 0) {
            out[OFF_IDX + (size_t)t * 2 + 0] = (float)i1;
            out[OFF_IDX + (size_t)t * 2 + 1] = (float)i2;
            out[OFF_TSC + (size_t)t * 2 + 0] = __expf(v1 - mx) * inv;
            out[OFF_TSC + (size_t)t * 2 + 1] = __expf(v2 - mx) * inv;
            if ((v1 - v2 < TAU) || (v2 - v3 < TAU)) {
                int slot = atomicAdd(cnt, 1);
                list[slot] = t;
            }
        }
    }
}

// ---------------------------------------------------------------------------
// Kernel B: exact np-chain recompute for flagged tokens (R3-R12 verified).
// ---------------------------------------------------------------------------
__global__ __launch_bounds__(256, 2) void router_exact(
        const float* __restrict__ X, const float* __restrict__ W,
        const float* __restrict__ Bb, float* __restrict__ out,
        const int* __restrict__ cnt, const int* __restrict__ list) {
    __shared__ float xrow[2048];
    __shared__ char  wbuf[2][64 * 272] __attribute__((aligned(16)));
    const int tid = threadIdx.x;
    const int n   = *cnt;

    for (int ii = blockIdx.x; ii < n; ii += gridDim.x) {
        const int t = list[ii];
#pragma unroll
        for (int q = 0; q < 2; ++q) {
            int s = tid + q * 256;
            *(f32x4*)&xrow[s * 4] = *(const f32x4*)(X + (size_t)t * DIM + s * 4);
        }
#pragma unroll
        for (int q = 0; q < 4; ++q) {
            int s = tid + q * 256;
            int e = s >> 4, dq = s & 15;
            f32x4 wv = *(const f32x4*)(W + (size_t)e * DIM + dq * 4);
            *(f32x4*)(wbuf[0] + e * 272 + ((16 * dq) ^ ((e & 7) << 4))) = wv;
        }
        __syncthreads();

        float acc = 0.0f;
#pragma unroll 1
        for (int c = 0; c < 32; ++c) {
            if (c + 1 < 32) {
#pragma unroll
                for (int q = 0; q < 4; ++q) {
                    int s = tid + q * 256;
                    int e = s >> 4, dq = s & 15;
                    f32x4 wv = *(const f32x4*)(W + (size_t)e * DIM + (c + 1) * 64 + dq * 4);
                    *(f32x4*)(wbuf[(c + 1) & 1] + e * 272 + ((16 * dq) ^ ((e & 7) << 4))) = wv;
                }
            }
            if (tid < 64) {
                const char* wb = wbuf[c & 1] + tid * 272;
                const int sw = (tid & 7) << 4;
#pragma unroll
                for (int dq = 0; dq < 16; ++dq) {
                    f32x4 xq = *(const f32x4*)&xrow[c * 64 + dq * 4];
                    f32x4 wv = *(const f32x4*)(wb + ((16 * dq) ^ sw));
#pragma unroll
                    for (int j = 0; j < 4; ++j)
                        acc = fmaf(xq[j], wv[j], acc);   // strict ascending d
                }
            }
            __syncthreads();
        }

        if (tid < 64) {
            const int lane = tid;
            const float lg = acc + Bb[lane];
            float m = lg;
#pragma unroll
            for (int s = 1; s < 64; s <<= 1) m = fmaxf(m, __shfl_xor(m, s, 64));
            const float p = __expf(lg - m);
            float den = p;
#pragma unroll
            for (int s = 1; s < 64; s <<= 1) den += __shfl_xor(den, s, 64);
            const float inv = 1.0f / den;
            out[(size_t)t * 64 + lane] = p * inv;

            float v1 = lg, v2 = -3.4e38f;
            int   i1 = lane, i2 = 127;
#pragma unroll
            for (int s = 1; s < 64; s <<= 1) {
                float ov1 = __shfl_xor(v1, s, 64), ov2 = __shfl_xor(v2, s, 64);
                int   oi1 = __shfl_xor(i1, s, 64), oi2 = __shfl_xor(i2, s, 64);
                bool  aw  = gtie(v1, i1, ov1, oi1);
                float nv1 = aw ? v1 : ov1;  int ni1 = aw ? i1 : oi1;
                float cv  = aw ? ov1 : v1;  int ci  = aw ? oi1 : i1;
                float sv  = aw ? v2 : ov2;  int si  = aw ? i2 : oi2;
                bool  c2  = gtie(cv, ci, sv, si);
                v1 = nv1; i1 = ni1;
                v2 = c2 ? cv : sv; i2 = c2 ? ci : si;
            }
            if (lane == 0) {
                out[OFF_IDX + (size_t)t * 2 + 0] = (float)i1;
                out[OFF_IDX + (size_t)t * 2 + 1] = (float)i2;
                out[OFF_TSC + (size_t)t * 2 + 0] = __expf(v1 - m) * inv;
                out[OFF_TSC + (size_t)t * 2 + 1] = __expf(v2 - m) * inv;
            }
        }
        __syncthreads();
    }
}

extern "C" void kernel_launch(void* const* d_in, const int* in_sizes, int n_in,
                              void* d_out, int out_size, void* d_ws, size_t ws_size,
                              hipStream_t stream) {
    const float* X = (const float*)d_in[0];   // [4,8192,2048] f32
    const float* W = (const float*)d_in[1];   // [64,2048] f32
    const float* b = (const float*)d_in[2];   // [64] f32
    float* out  = (float*)d_out;
    short* Wsp  = (short*)d_ws;                       // 512 KB
    int*   cnt  = (int*)((char*)d_ws + 524288);       // 4 B
    int*   list = (int*)((char*)d_ws + 524292);       // up to 128 KB

    wsplit<<<1024, 256, 0, stream>>>(W, Wsp, cnt);
    router_mfma<<<NTOK / 16, 64, 0, stream>>>(X, Wsp, b, out, cnt, list);
    router_exact<<<512, 256, 0, stream>>>(X, W, b, out, cnt, list);
}

// Round 15
// 97.899 us; speedup vs baseline: 1.7425x; 1.7099x over previous
//
#include <hip/hip_runtime.h>
#include <hip/hip_bf16.h>
#include <stdint.h>
#include <stddef.h>

#define DIM   2048
#define NEXP  64
#define NTOK  32768
#define KF    64                       // 2048/32 k-fragments (global)
#define OFF_IDX  (NTOK*NEXP)           // 2097152
#define OFF_TSC  (OFF_IDX + NTOK*2)    // 2162688
#define TAU   5e-4f

typedef __attribute__((ext_vector_type(8))) short  short8;
typedef __attribute__((ext_vector_type(4))) float  f32x4;

__device__ __forceinline__ unsigned short bf16_rne(float f) {
    unsigned u = __builtin_bit_cast(unsigned, f);
    u += 0x7fffu + ((u >> 16) & 1u);
    return (unsigned short)(u >> 16);
}
__device__ __forceinline__ float bf16_up(unsigned short s) {
    unsigned u = ((unsigned)s) << 16;
    return __builtin_bit_cast(float, u);
}

// ---------------------------------------------------------------------------
// Pre-kernel: split W into 2 bf16 terms (hi/mid) in MFMA B-fragment order.
// byte(term,kf,nf,lane) = (((term*64+kf)*4+nf)*64+lane)*16.  512 KB total.
// Also zeroes the ambiguous-token counter.
// ---------------------------------------------------------------------------
__global__ __launch_bounds__(256) void wsplit(const float* __restrict__ W,
                                              short* __restrict__ warr,
                                              int* __restrict__ cnt) {
    int idx  = blockIdx.x * 256 + threadIdx.x;   // 0..262143
    if (idx == 0) *cnt = 0;
    int j    = idx & 7;
    int lane = (idx >> 3) & 63;
    int nf   = (idx >> 9) & 3;
    int kf   = (idx >> 11) & 63;
    int term = idx >> 17;                        // 0..1
    int e = nf * 16 + (lane & 15);
    int d = kf * 32 + (lane >> 4) * 8 + j;
    float w = W[e * DIM + d];
    unsigned short h  = bf16_rne(w);
    float r1 = w - bf16_up(h);
    unsigned short md = bf16_rne(r1);
    warr[idx] = (short)((term == 0) ? h : md);
}

__device__ __forceinline__ bool gtie(float a, int ia, float b, int ib) {
    return (a > b) || (a == b && ia < ib);
}

// ---------------------------------------------------------------------------
// Kernel A (R15): B-stream fix. Block = 512 thr (8 waves) = 64 tokens.
// Waves 0-3: K-half 0 (kf 0..31), waves 4-7: K-half 1 (kf 32..63); wave wq
// owns tokens [bx*64+wq*16, +16). Per 4-kf GROUP the block cooperatively
// stages both halves' B (64 KB) into LDS (linear copy, coalesced 1KB bursts)
// -> B global traffic 1GB -> 256MB; inner loop reads B via ds_read_b128
// (lane*16 contiguous, conflict-free). A: 2-deep register ring from HBM.
// 4096 waves = 16/CU (4/SIMD). K-halves merged via LDS (R10-verified);
// numerics + epilogue + TAU flag byte-identical to R8/R10 (passed).
// ---------------------------------------------------------------------------
__global__ __launch_bounds__(512, 4) void router_mfma(
        const float* __restrict__ X, const short* __restrict__ Wsp,
        const float* __restrict__ bias, float* __restrict__ out,
        int* __restrict__ cnt, int* __restrict__ list) {
    __shared__ char smem[65536] __attribute__((aligned(16)));
    const int tid  = threadIdx.x;
    const int lane = tid & 63;
    const int w    = tid >> 6;                 // 0..7
    const int wq   = w & 3;                    // token group
    const int kh   = w >> 2;                   // K-half
    const int tok0 = blockIdx.x * 64 + wq * 16;
    const int l15  = lane & 15;
    const int l4   = lane >> 4;

    // ---- staging map: quadrant q2 = (khs, ts); 128 thr copy 16 KB --------
    const int q2  = tid >> 7;                  // 0..3
    const int khs = q2 >> 1, ts = q2 & 1;
    const int li  = tid & 127;
    const char* wsrc = (const char*)Wsp + ((size_t)ts * 64 + khs * 32) * 4096 + li * 16;
    char* bdst = smem + q2 * 16384 + li * 16;

    // ---- compute-side maps -------------------------------------------------
    const float* xr = X + (size_t)(tok0 + l15) * DIM + kh * 1024 + l4 * 8;
    const char*  bq = smem + (kh * 2) * 16384 + lane * 16;  // +t*16384+kf'*4096+nf*1024

    f32x4 acc[4];
#pragma unroll
    for (int n = 0; n < 4; n++) acc[n] = (f32x4)0.0f;

    // A-ring 2-deep (local kf 0..31)
    f32x4 a_pf[2][2];
#pragma unroll
    for (int p = 0; p < 2; p++) {
        a_pf[p][0] = *(const f32x4*)(xr + p * 32);
        a_pf[p][1] = *(const f32x4*)(xr + p * 32 + 4);
    }

#pragma unroll 1
    for (int g = 0; g < 8; ++g) {
        __syncthreads();                       // group g-1 reads done
        // stage group g: 8 x (dwordx4 load -> ds_write), verbatim copy
        {
            const char* s0 = wsrc + g * 16384;
            f32x4 ld[8];
#pragma unroll
            for (int i = 0; i < 8; i++) ld[i] = *(const f32x4*)(s0 + i * 2048);
#pragma unroll
            for (int i = 0; i < 8; i++) *(f32x4*)(bdst + i * 2048) = ld[i];
        }
        __syncthreads();                       // B group g visible

#pragma unroll
        for (int p = 0; p < 4; ++p) {
            const int lkf = g * 4 + p;
            const int kn  = (lkf + 2 < 32) ? lkf + 2 : 31;
            const int s   = p & 1;

            // consume A slot, reissue for lkf+2
            f32x4 a0 = a_pf[s][0], a1 = a_pf[s][1];
            a_pf[s][0] = *(const f32x4*)(xr + kn * 32);
            a_pf[s][1] = *(const f32x4*)(xr + kn * 32 + 4);

            // B fragments from LDS (kf' = p)
            short8 b[2][4];
#pragma unroll
            for (int t = 0; t < 2; t++)
#pragma unroll
                for (int n = 0; n < 4; n++)
                    b[t][n] = *(const short8*)(bq + t * 16384 + p * 4096 + n * 1024);

            // 2-way bf16 split of A (identical math to R8)
            short8 ah, am;
#pragma unroll
            for (int j = 0; j < 8; j++) {
                float v = (j < 4) ? a0[j & 3] : a1[j & 3];
                unsigned short h  = bf16_rne(v);
                float r1 = v - bf16_up(h);
                unsigned short md = bf16_rne(r1);
                ah[j] = (short)h;
                am[j] = (short)md;
            }

#pragma unroll
            for (int n = 0; n < 4; n++) {
                f32x4 c = acc[n];
                c = __builtin_amdgcn_mfma_f32_16x16x32_bf16(ah, b[0][n], c, 0, 0, 0);
                c = __builtin_amdgcn_mfma_f32_16x16x32_bf16(ah, b[1][n], c, 0, 0, 0);
                c = __builtin_amdgcn_mfma_f32_16x16x32_bf16(am, b[0][n], c, 0, 0, 0);
                c = __builtin_amdgcn_mfma_f32_16x16x32_bf16(am, b[1][n], c, 0, 0, 0);
                acc[n] = c;
            }
        }
    }

    // ---------------- merge K-halves via LDS (R10-verified pattern) --------
    __syncthreads();                           // B reads done; smem reusable
    if (kh == 1) {
#pragma unroll
        for (int n = 0; n < 4; n++)
            *(f32x4*)(smem + ((size_t)(wq * 4 + n)) * 1024 + lane * 16) = acc[n];
    }
    __syncthreads();
    if (kh == 1) return;
#pragma unroll
    for (int n = 0; n < 4; n++)
        acc[n] += *(const f32x4*)(smem + ((size_t)(wq * 4 + n)) * 1024 + lane * 16);

    // ------------- epilogue: bias + softmax + top-3 + flag (R8-verified) ---
    float bv[4];
#pragma unroll
    for (int n = 0; n < 4; n++) bv[n] = bias[n * 16 + l15];

#pragma unroll
    for (int r = 0; r < 4; r++) {
        const int t = tok0 + l4 * 4 + r;       // C row = (lane>>4)*4+reg
        float v[4];
#pragma unroll
        for (int n = 0; n < 4; n++) v[n] = acc[n][r] + bv[n];

        float mx = fmaxf(fmaxf(v[0], v[1]), fmaxf(v[2], v[3]));
#pragma unroll
        for (int s = 1; s < 16; s <<= 1) mx = fmaxf(mx, __shfl_xor(mx, s, 64));

        float p[4], den = 0.0f;
#pragma unroll
        for (int n = 0; n < 4; n++) { p[n] = __expf(v[n] - mx); den += p[n]; }
#pragma unroll
        for (int s = 1; s < 16; s <<= 1) den += __shfl_xor(den, s, 64);
        const float inv = 1.0f / den;
#pragma unroll
        for (int n = 0; n < 4; n++)
            out[(size_t)t * 64 + n * 16 + l15] = p[n] * inv;

        float v1 = -3.4e38f, v2 = -3.4e38f, v3 = -3.4e38f;
        int   i1 = 9999,     i2 = 9999,     i3 = 9999;
#pragma unroll
        for (int n = 0; n < 4; n++) {
            float vv = v[n]; int ii = n * 16 + l15;
            if (gtie(vv, ii, v1, i1))      { v3=v2;i3=i2; v2=v1;i2=i1; v1=vv;i1=ii; }
            else if (gtie(vv, ii, v2, i2)) { v3=v2;i3=i2; v2=vv;i2=ii; }
            else if (gtie(vv, ii, v3, i3)) { v3=vv;i3=ii; }
        }
#pragma unroll
        for (int s = 1; s < 16; s <<= 1) {
            float ov1=__shfl_xor(v1,s,64), ov2=__shfl_xor(v2,s,64), ov3=__shfl_xor(v3,s,64);
            int   oi1=__shfl_xor(i1,s,64), oi2=__shfl_xor(i2,s,64), oi3=__shfl_xor(i3,s,64);
            bool a1 = gtie(v1,i1,ov1,oi1);
            float w1 = a1?v1:ov1;  int k1 = a1?i1:oi1;
            float x1 = a1?v2:ov2;  int xi1= a1?i2:oi2;
            float x2 = a1?v3:ov3;  int xi2= a1?i3:oi3;
            float y1 = a1?ov1:v1;  int yi1= a1?oi1:i1;
            float y2 = a1?ov2:v2;  int yi2= a1?oi2:i2;
            bool a2 = gtie(x1,xi1,y1,yi1);
            float w2 = a2?x1:y1;   int k2 = a2?xi1:yi1;
            float w3; int k3;
            if (a2) { bool a3 = gtie(x2,xi2,y1,yi1); w3 = a3?x2:y1; k3 = a3?xi2:yi1; }
            else    { bool a3 = gtie(x1,xi1,y2,yi2); w3 = a3?x1:y2; k3 = a3?xi1:yi2; }
            v1=w1;i1=k1; v2=w2;i2=k2; v3=w3;i3=k3;
        }
        if (l15 == 0) {
            out[OFF_IDX + (size_t)t * 2 + 0] = (float)i1;
            out[OFF_IDX + (size_t)t * 2 + 1] = (float)i2;
            out[OFF_TSC + (size_t)t * 2 + 0] = __expf(v1 - mx) * inv;
            out[OFF_TSC + (size_t)t * 2 + 1] = __expf(v2 - mx) * inv;
            if ((v1 - v2 < TAU) || (v2 - v3 < TAU)) {
                int slot = atomicAdd(cnt, 1);
                list[slot] = t;
            }
        }
    }
}

// ---------------------------------------------------------------------------
// Kernel B: exact np-chain recompute for flagged tokens (R3-R12 verified).
// ---------------------------------------------------------------------------
__global__ __launch_bounds__(256, 2) void router_exact(
        const float* __restrict__ X, const float* __restrict__ W,
        const float* __restrict__ Bb, float* __restrict__ out,
        const int* __restrict__ cnt, const int* __restrict__ list) {
    __shared__ float xrow[2048];
    __shared__ char  wbuf[2][64 * 272] __attribute__((aligned(16)));
    const int tid = threadIdx.x;
    const int n   = *cnt;

    for (int ii = blockIdx.x; ii < n; ii += gridDim.x) {
        const int t = list[ii];
#pragma unroll
        for (int q = 0; q < 2; ++q) {
            int s = tid + q * 256;
            *(f32x4*)&xrow[s * 4] = *(const f32x4*)(X + (size_t)t * DIM + s * 4);
        }
#pragma unroll
        for (int q = 0; q < 4; ++q) {
            int s = tid + q * 256;
            int e = s >> 4, dq = s & 15;
            f32x4 wv = *(const f32x4*)(W + (size_t)e * DIM + dq * 4);
            *(f32x4*)(wbuf[0] + e * 272 + ((16 * dq) ^ ((e & 7) << 4))) = wv;
        }
        __syncthreads();

        float acc = 0.0f;
#pragma unroll 1
        for (int c = 0; c < 32; ++c) {
            if (c + 1 < 32) {
#pragma unroll
                for (int q = 0; q < 4; ++q) {
                    int s = tid + q * 256;
                    int e = s >> 4, dq = s & 15;
                    f32x4 wv = *(const f32x4*)(W + (size_t)e * DIM + (c + 1) * 64 + dq * 4);
                    *(f32x4*)(wbuf[(c + 1) & 1] + e * 272 + ((16 * dq) ^ ((e & 7) << 4))) = wv;
                }
            }
            if (tid < 64) {
                const char* wb = wbuf[c & 1] + tid * 272;
                const int sw = (tid & 7) << 4;
#pragma unroll
                for (int dq = 0; dq < 16; ++dq) {
                    f32x4 xq = *(const f32x4*)&xrow[c * 64 + dq * 4];
                    f32x4 wv = *(const f32x4*)(wb + ((16 * dq) ^ sw));
#pragma unroll
                    for (int j = 0; j < 4; ++j)
                        acc = fmaf(xq[j], wv[j], acc);   // strict ascending d
                }
            }
            __syncthreads();
        }

        if (tid < 64) {
            const int lane = tid;
            const float lg = acc + Bb[lane];
            float m = lg;
#pragma unroll
            for (int s = 1; s < 64; s <<= 1) m = fmaxf(m, __shfl_xor(m, s, 64));
            const float p = __expf(lg - m);
            float den = p;
#pragma unroll
            for (int s = 1; s < 64; s <<= 1) den += __shfl_xor(den, s, 64);
            const float inv = 1.0f / den;
            out[(size_t)t * 64 + lane] = p * inv;

            float v1 = lg, v2 = -3.4e38f;
            int   i1 = lane, i2 = 127;
#pragma unroll
            for (int s = 1; s < 64; s <<= 1) {
                float ov1 = __shfl_xor(v1, s, 64), ov2 = __shfl_xor(v2, s, 64);
                int   oi1 = __shfl_xor(i1, s, 64), oi2 = __shfl_xor(i2, s, 64);
                bool  aw  = gtie(v1, i1, ov1, oi1);
                float nv1 = aw ? v1 : ov1;  int ni1 = aw ? i1 : oi1;
                float cv  = aw ? ov1 : v1;  int ci  = aw ? oi1 : i1;
                float sv  = aw ? v2 : ov2;  int si  = aw ? i2 : oi2;
                bool  c2  = gtie(cv, ci, sv, si);
                v1 = nv1; i1 = ni1;
                v2 = c2 ? cv : sv; i2 = c2 ? ci : si;
            }
            if (lane == 0) {
                out[OFF_IDX + (size_t)t * 2 + 0] = (float)i1;
                out[OFF_IDX + (size_t)t * 2 + 1] = (float)i2;
                out[OFF_TSC + (size_t)t * 2 + 0] = __expf(v1 - m) * inv;
                out[OFF_TSC + (size_t)t * 2 + 1] = __expf(v2 - m) * inv;
            }
        }
        __syncthreads();
    }
}

extern "C" void kernel_launch(void* const* d_in, const int* in_sizes, int n_in,
                              void* d_out, int out_size, void* d_ws, size_t ws_size,
                              hipStream_t stream) {
    const float* X = (const float*)d_in[0];   // [4,8192,2048] f32
    const float* W = (const float*)d_in[1];   // [64,2048] f32
    const float* b = (const float*)d_in[2];   // [64] f32
    float* out  = (float*)d_out;
    short* Wsp  = (short*)d_ws;                       // 512 KB
    int*   cnt  = (int*)((char*)d_ws + 524288);       // 4 B
    int*   list = (int*)((char*)d_ws + 524292);       // up to 128 KB

    wsplit<<<1024, 256, 0, stream>>>(W, Wsp, cnt);
    router_mfma<<<NTOK / 64, 512, 0, stream>>>(X, Wsp, b, out, cnt, list);
    router_exact<<<512, 256, 0, stream>>>(X, W, b, out, cnt, list);
}